// Round 16
// baseline (278.414 us; speedup 1.0000x reference)
//
#include <hip/hip_runtime.h>
#include <hip/hip_fp16.h>

#define BB 8
#define TT 12
#define NN 10000
#define HH 32
#define EE 320000
#define HOR 12
#define NCB 157   // ceil(NN/64) CB blocks in k_cbhist

typedef unsigned long long ull;

static __device__ __forceinline__ float sigm(float x) {
    return __builtin_amdgcn_rcpf(1.0f + __expf(-x));
}
static __device__ __forceinline__ float tanh_fast(float x) {
    return 1.0f - 2.0f * __builtin_amdgcn_rcpf(1.0f + __expf(2.0f * x));
}
static __device__ __forceinline__ float2 uph2(unsigned u) {
    __half2 h = *(__half2*)&u;
    return __half22float2(h);
}
static __device__ __forceinline__ unsigned pkh2(float a, float b) {
    __half2 h = __floats2half2_rn(a, b);
    return *(unsigned*)&h;
}

typedef _Float16 f16x4 __attribute__((ext_vector_type(4)));
typedef float    f32x4 __attribute__((ext_vector_type(4)));

// ---- zero the counter region
__global__ void k_zero(uint4* __restrict__ p, int n4) {
    int i = blockIdx.x * blockDim.x + threadIdx.x;
    if (i < n4) p[i] = (uint4){0u, 0u, 0u, 0u};
}

// ---- fused: CB GEMM-style (0..156), tiny prep (157), edge histogram+RANK (158..1407)
__global__ void k_cbhist(const float* __restrict__ node_emb, const float* __restrict__ enc_b,
                     const float* __restrict__ w_ih, const float* __restrict__ b_ih,
                     const float* __restrict__ b_hh,
                     const float* __restrict__ enc_w, const float* __restrict__ filt_w,
                     const float* __restrict__ filt_b, const float* __restrict__ dec_w,
                     const float* __restrict__ dec_b,
                     float* __restrict__ CB, float* __restrict__ A,
                     float* __restrict__ W2, float* __restrict__ b2,
                     const int* __restrict__ ei,
                     int* cnt_f, int* cnt_b,
                     int* __restrict__ rank_f, int* __restrict__ rank_b) {
    __shared__ float sw[96*36];
    __shared__ float semb[64*36];
    __shared__ float sbias[96];
    int bid = blockIdx.x;
    int tid = threadIdx.x;
    if (bid < NCB) {               // CB: 64 nodes/block, LDS-staged, coalesced
        int n0 = bid * 64;
        for (int i = tid; i < 96*32; i += 256) {
            int g = i >> 5, h = i & 31;
            sw[g*36 + h] = w_ih[i];
        }
        for (int i = tid; i < 64*32; i += 256) {
            int row = i >> 5, h = i & 31;
            int n = n0 + row; if (n >= NN) n = NN-1;
            semb[row*36 + h] = enc_b[h] + node_emb[(size_t)n*32 + h];
        }
        if (tid < 96) sbias[tid] = b_ih[tid] + (tid < 64 ? b_hh[tid] : 0.f);
        __syncthreads();
        #pragma unroll 1
        for (int i = 0; i < 24; i++) {
            int o = i*256 + tid;
            int row = o / 96, g = o - row*96;
            int n = n0 + row;
            if (n < NN) {
                float s = sbias[g];
                const float4* ev = (const float4*)(semb + row*36);
                const float4* wv = (const float4*)(sw + g*36);
                #pragma unroll
                for (int q = 0; q < 8; q++) {
                    float4 e = ev[q], w = wv[q];
                    s = fmaf(e.x, w.x, s); s = fmaf(e.y, w.y, s);
                    s = fmaf(e.z, w.z, s); s = fmaf(e.w, w.w, s);
                }
                CB[(size_t)n*96 + g] = s;
            }
        }
    } else if (bid == NCB) {       // prep
        for (int i = tid; i < 96 + 160*12 + 12; i += blockDim.x) {
            if (i < 96) {
                float s = 0.f;
                for (int h = 0; h < HH; h++) s += enc_w[h] * w_ih[i*HH + h];
                A[i] = s;
            } else if (i < 96 + 1920) {
                int j = i - 96; int c = j / 12, o = j % 12;
                float s = 0.f;
                for (int h = 0; h < HH; h++) s += filt_w[c*HH + h] * dec_w[h*12 + o];
                W2[j] = s;
            } else {
                int o = i - 2016;
                float s = dec_b[o];
                for (int h = 0; h < HH; h++) s += filt_b[h] * dec_w[h*12 + o];
                b2[o] = s;
            }
        }
    } else {                       // histogram + rank capture
        int e = (bid - NCB - 1) * 256 + tid;
        int s = ei[e], t = ei[EE + e];
        rank_f[e] = atomicAdd(&cnt_f[t], 1);
        rank_b[e] = atomicAdd(&cnt_b[s], 1);
    }
}

// ---- single-block exclusive scan (2 blocks: fwd / bwd)
__global__ void k_scan(const int* __restrict__ cnt_f, int* off_f,
                       const int* __restrict__ cnt_b, int* off_b) {
    const int* cnt; int* off;
    if (blockIdx.x == 0) { cnt = cnt_f; off = off_f; }
    else                 { cnt = cnt_b; off = off_b; }
    __shared__ int part[1024];
    int t = threadIdx.x;
    const int CH = (NN + 1023) / 1024;  // 10
    int beg = t * CH, end = min(beg + CH, NN);
    int s = 0;
    for (int i = beg; i < end; i++) s += cnt[i];
    part[t] = s;
    __syncthreads();
    for (int d = 1; d < 1024; d <<= 1) {
        int add = (t >= d) ? part[t - d] : 0;
        __syncthreads();
        part[t] += add;
        __syncthreads();
    }
    int run = part[t] - s;
    for (int i = beg; i < end; i++) {
        off[i] = run; run += cnt[i];
    }
    if (t == 1023) off[NN] = part[1023];
}

// ---- fused GRU (blocks 0..1249) + atomic-free CSR fill (blocks 1250..2499)
// GRU output now in BATCH-SLAB layout: [slice=b>>1][n][b&1][h] fp16 (128B rows)
// so diffusion gathers have a 1.28MB/slab working set (fits one XCD's L2).
__global__ __launch_bounds__(256) void k_grufill(const float* __restrict__ x,
                      const float* __restrict__ CB, const float* __restrict__ Ag,
                      const float* __restrict__ w_hh, const float* __restrict__ b_hh,
                      __half* __restrict__ hout16,
                      const int* __restrict__ ei, const float* __restrict__ ew,
                      const int* __restrict__ off_f, const int* __restrict__ rank_f,
                      ull* __restrict__ cfe,
                      const int* __restrict__ off_b, const int* __restrict__ rank_b,
                      ull* __restrict__ cbe) {
    int tid = threadIdx.x;
    if (blockIdx.x >= 1250) {      // ---- fill: packed (w<<32|idx), atomic-free
        int e = (blockIdx.x - 1250) * 256 + tid;
        int s = ei[e], t = ei[EE + e]; float w = ew[e];
        ull wb = (ull)__float_as_uint(w) << 32;
        cfe[off_f[t] + rank_f[e]] = wb | (unsigned)s;
        cbe[off_b[s] + rank_b[e]] = wb | (unsigned)t;
        return;
    }
    // ---- MFMA GRU section (verified, unchanged logic)
    __shared__ unsigned sW[1536];
    __shared__ __half  shh[4][16*40];
    __shared__ float   sx[64][12];
    int r0b = blockIdx.x * 64;

    for (int d = tid; d < 1536; d += 256) {
        int fi = d >> 1, epair = d & 1;
        int l = fi & 63, tk = fi >> 6;
        int gt = tk >> 1, kh = tk & 1;
        int gate = 16*gt + (l & 15);
        int k = kh*16 + ((l >> 4) << 2) + 2*epair;
        sW[d] = pkh2(w_hh[gate*32 + k], w_hh[gate*32 + k + 1]);
    }
    for (int i = tid; i < 64*12; i += 256) {
        int row = i / 12, t = i - row*12;
        int r = r0b + row; int b = r / NN, n = r - b*NN;
        sx[row][t] = x[((size_t)b*TT + t)*NN + n];
    }
    __syncthreads();

    const int wv = tid >> 6, l = tid & 63;
    const int c = l & 15, m = l >> 4;
    const int r0w = r0b + wv*16;

    int bb[4], nn_[4];
    #pragma unroll
    for (int q = 0; q < 4; q++) {
        int r = r0w + 4*m + q;
        bb[q] = r / NN; nn_[q] = r - bb[q]*NN;
    }

    float cNx[2][4];
    f32x4 crv[2], czv[2], cnv[2];
    float aRj[2], aZj[2], aNj[2], bn0c[2];
    #pragma unroll
    for (int t2 = 0; t2 < 2; t2++) {
        int j = 16*t2 + c;
        #pragma unroll
        for (int q = 0; q < 4; q++) {
            const float* cb = CB + (size_t)nn_[q]*96;
            crv[t2][q] = cb[j];
            czv[t2][q] = cb[32 + j];
            cNx[t2][q] = cb[64 + j];
        }
        bn0c[t2] = b_hh[64 + j];
        cnv[t2] = (f32x4){bn0c[t2], bn0c[t2], bn0c[t2], bn0c[t2]};
        aRj[t2] = Ag[j]; aZj[t2] = Ag[32 + j]; aNj[t2] = Ag[64 + j];
    }

    f16x4 bf[12];
    #pragma unroll
    for (int i = 0; i < 12; i++) {
        ull v = *(const ull*)(sW + (i*64 + l)*2);
        bf[i] = __builtin_bit_cast(f16x4, v);
    }

    __half* hb = shh[wv];
    float own[2][4];
    {
        #pragma unroll
        for (int t2 = 0; t2 < 2; t2++)
        #pragma unroll
        for (int q = 0; q < 4; q++) {
            float xv = sx[wv*16 + 4*m + q][0];
            float rr = sigm(fmaf(xv, aRj[t2], crv[t2][q]));
            float zz = sigm(fmaf(xv, aZj[t2], czv[t2][q]));
            float nv = tanh_fast(fmaf(xv, aNj[t2], cNx[t2][q]) + rr * bn0c[t2]);
            own[t2][q] = (1.f - zz) * nv;
        }
    }
    #pragma unroll
    for (int t2 = 0; t2 < 2; t2++)
    #pragma unroll
    for (int q = 0; q < 4; q++)
        hb[(4*m + q)*40 + 16*t2 + c] = __float2half_rn(own[t2][q]);

    #pragma unroll 1
    for (int t = 1; t < TT; t++) {
        asm volatile("s_waitcnt lgkmcnt(0)" ::: "memory");
        __builtin_amdgcn_sched_barrier(0);
        ull va0 = *(const ull*)(hb + c*40 + m*4);
        ull va1 = *(const ull*)(hb + c*40 + 16 + m*4);
        f16x4 a0 = __builtin_bit_cast(f16x4, va0);
        f16x4 a1 = __builtin_bit_cast(f16x4, va1);
        float xq[4];
        #pragma unroll
        for (int q = 0; q < 4; q++) xq[q] = sx[wv*16 + 4*m + q][t];

        f32x4 aR[2], aZ[2], aN[2];
        #pragma unroll
        for (int t2 = 0; t2 < 2; t2++) {
            aR[t2] = __builtin_amdgcn_mfma_f32_16x16x16f16(a0, bf[(t2    )*2    ], crv[t2], 0, 0, 0);
            aR[t2] = __builtin_amdgcn_mfma_f32_16x16x16f16(a1, bf[(t2    )*2 + 1], aR[t2], 0, 0, 0);
            aZ[t2] = __builtin_amdgcn_mfma_f32_16x16x16f16(a0, bf[(2 + t2)*2    ], czv[t2], 0, 0, 0);
            aZ[t2] = __builtin_amdgcn_mfma_f32_16x16x16f16(a1, bf[(2 + t2)*2 + 1], aZ[t2], 0, 0, 0);
            aN[t2] = __builtin_amdgcn_mfma_f32_16x16x16f16(a0, bf[(4 + t2)*2    ], cnv[t2], 0, 0, 0);
            aN[t2] = __builtin_amdgcn_mfma_f32_16x16x16f16(a1, bf[(4 + t2)*2 + 1], aN[t2], 0, 0, 0);
        }
        #pragma unroll
        for (int t2 = 0; t2 < 2; t2++)
        #pragma unroll
        for (int q = 0; q < 4; q++) {
            float rr = sigm(fmaf(xq[q], aRj[t2], aR[t2][q]));
            float zz = sigm(fmaf(xq[q], aZj[t2], aZ[t2][q]));
            float nv = tanh_fast(fmaf(xq[q], aNj[t2], cNx[t2][q]) + rr * aN[t2][q]);
            own[t2][q] = (1.f - zz) * nv + zz * own[t2][q];
        }
        if (t < TT-1) {
            #pragma unroll
            for (int t2 = 0; t2 < 2; t2++)
            #pragma unroll
            for (int q = 0; q < 4; q++)
                hb[(4*m + q)*40 + 16*t2 + c] = __float2half_rn(own[t2][q]);
        }
    }
    #pragma unroll
    for (int t2 = 0; t2 < 2; t2++)
    #pragma unroll
    for (int q = 0; q < 4; q++) {
        size_t idx = ((size_t)((bb[q] >> 1)*NN + nn_[q]) << 6)
                   + ((bb[q] & 1) << 5) + 16*t2 + c;
        hout16[idx] = __float2half(own[t2][q]);
    }
}

// ---- sliced gather for one (slice, node, dir): 2 lane-groups (eg), lane owns
// dword `sub` of the 128B slab row; 4 independent chains per iter (8 edges);
// ef loads non-temporal (don't evict resident state); final xor-32 reduce.
static __device__ __forceinline__ void gather_slice(
        const unsigned* __restrict__ xu, unsigned rowbase /*s*NN*/,
        const ull* __restrict__ ef, int e0, int e1, int eg, int sub,
        float& a0, float& a1) {
    float ws = 0.f;
    a0 = 0.f; a1 = 0.f;
    for (int e = e0; e < e1; e += 8) {
        int ee0 = e + eg, ee1 = e + 2 + eg, ee2 = e + 4 + eg, ee3 = e + 6 + eg;
        ull q0 = ee0 < e1 ? __builtin_nontemporal_load(ef + ee0) : 0ULL;
        ull q1 = ee1 < e1 ? __builtin_nontemporal_load(ef + ee1) : 0ULL;
        ull q2 = ee2 < e1 ? __builtin_nontemporal_load(ef + ee2) : 0ULL;
        ull q3 = ee3 < e1 ? __builtin_nontemporal_load(ef + ee3) : 0ULL;
        float w0 = __uint_as_float((unsigned)(q0 >> 32));
        float w1 = __uint_as_float((unsigned)(q1 >> 32));
        float w2 = __uint_as_float((unsigned)(q2 >> 32));
        float w3 = __uint_as_float((unsigned)(q3 >> 32));
        unsigned u0 = xu[((size_t)(rowbase + (unsigned)q0) << 5) + sub];
        unsigned u1 = xu[((size_t)(rowbase + (unsigned)q1) << 5) + sub];
        unsigned u2 = xu[((size_t)(rowbase + (unsigned)q2) << 5) + sub];
        unsigned u3 = xu[((size_t)(rowbase + (unsigned)q3) << 5) + sub];
        ws += (w0 + w1) + (w2 + w3);
        float2 f;
        f = uph2(u0); a0 = fmaf(w0, f.x, a0); a1 = fmaf(w0, f.y, a1);
        f = uph2(u1); a0 = fmaf(w1, f.x, a0); a1 = fmaf(w1, f.y, a1);
        f = uph2(u2); a0 = fmaf(w2, f.x, a0); a1 = fmaf(w2, f.y, a1);
        f = uph2(u3); a0 = fmaf(w3, f.x, a0); a1 = fmaf(w3, f.y, a1);
    }
    a0 += __shfl_xor(a0, 32);
    a1 += __shfl_xor(a1, 32);
    ws += __shfl_xor(ws, 32);
    float inv = ws > 0.f ? __builtin_amdgcn_rcpf(ws) : 1.0f;
    a0 *= inv; a1 *= inv;
}

// ---- hop 1, batch-sliced: block = (slice, 2 nodes x 2 dirs). Slice pinned to
// XCD pair via bid%8 round-robin heuristic (perf-only assumption).
__global__ __launch_bounds__(256) void k_prop(
        const __half* __restrict__ h16,
        __half* __restrict__ a16, __half* __restrict__ c16,
        const int* __restrict__ offF, const ull* __restrict__ efF,
        const int* __restrict__ offB, const ull* __restrict__ efB) {
    int bid = blockIdx.x;                 // 20000 blocks
    int s = (bid & 7) >> 1;
    int inner = (bid >> 3) * 2 + (bid & 1);   // 0..4999
    int wid = threadIdx.x >> 6, l = threadIdx.x & 63;
    int node = inner*2 + (wid >> 1), dir = wid & 1;
    int eg = l >> 5, sub = l & 31;
    unsigned rowbase = (unsigned)(s * NN);
    const int* off = dir ? offB : offF;
    const ull* ef = dir ? efB : efF;
    float a0, a1;
    gather_slice((const unsigned*)h16, rowbase, ef, off[node], off[node+1],
                 eg, sub, a0, a1);
    if (l < 32) {
        unsigned* y = (unsigned*)(dir ? c16 : a16);
        y[((size_t)(rowbase + node) << 5) + l] = pkh2(a0, a1);
    }
}

// ---- hop 2 + decoder, batch-sliced: gathers into LDS; decode covers the
// block's (2 nodes x 2 batches of slice s) reading h/fwd1/bwd1 slabs (L2-hot).
__global__ __launch_bounds__(256) void k_prop2dec(
        const __half* __restrict__ aF, const __half* __restrict__ cBk,
        const __half* __restrict__ h16,
        const int* __restrict__ offF, const ull* __restrict__ efF,
        const int* __restrict__ offB, const ull* __restrict__ efB,
        const float* __restrict__ W2, const float* __restrict__ b2,
        float* __restrict__ out) {
    __shared__ float sW[1920];
    __shared__ float sb[12];
    __shared__ unsigned spc[4][32];       // [wave = (nl,dir)][dwords of 128B slice row]
    int tid = threadIdx.x;
    for (int i = tid; i < 1920; i += 256) sW[i] = W2[i];
    if (tid < 12) sb[tid] = b2[tid];
    int bid = blockIdx.x;                 // 20000 blocks
    int s = (bid & 7) >> 1;
    int inner = (bid >> 3) * 2 + (bid & 1);
    int node0 = inner * 2;
    int wid = tid >> 6, l = tid & 63;
    int node = node0 + (wid >> 1), dir = wid & 1;
    int eg = l >> 5, sub = l & 31;
    unsigned rowbase = (unsigned)(s * NN);
    {
        const __half* src = dir ? cBk : aF;
        const int* off = dir ? offB : offF;
        const ull* ef = dir ? efB : efF;
        float a0, a1;
        gather_slice((const unsigned*)src, rowbase, ef, off[node], off[node+1],
                     eg, sub, a0, a1);
        if (l < 32) spc[wid][sub] = pkh2(a0, a1);
    }
    __syncthreads();
    if (tid < 48) {
        int p = tid / 12;            // 0..3 = (nl, bl)
        int o = tid - p*12;
        int nl = p >> 1, bl = p & 1;
        int nd = node0 + nl;
        int b = 2*s + bl;
        float acc = sb[o];
        size_t dbase = ((size_t)(rowbase + nd) << 5) + (bl << 4);  // 16 dwords
        // global pieces: h (W2 rows 0..31), fwd1 (32..63), bwd1 (96..127)
        const unsigned* gp[3] = {(const unsigned*)h16 + dbase,
                                 (const unsigned*)aF + dbase,
                                 (const unsigned*)cBk + dbase};
        const int wo[3] = {0, 32, 96};
        #pragma unroll
        for (int gi = 0; gi < 3; gi++) {
            const unsigned* pp = gp[gi];
            #pragma unroll
            for (int d = 0; d < 16; d++) {
                float2 f = uph2(pp[d]);
                acc = fmaf(f.x, sW[(wo[gi] + 2*d    )*12 + o], acc);
                acc = fmaf(f.y, sW[(wo[gi] + 2*d + 1)*12 + o], acc);
            }
        }
        // LDS pieces: fwd2 (rows 64..95) = spc[nl*2], bwd2 (128..159) = spc[nl*2+1]
        #pragma unroll
        for (int dd = 0; dd < 2; dd++) {
            const unsigned* pp = &spc[nl*2 + dd][bl << 4];
            int wbase = 64 + dd*64;
            #pragma unroll
            for (int d = 0; d < 16; d++) {
                float2 f = uph2(pp[d]);
                acc = fmaf(f.x, sW[(wbase + 2*d    )*12 + o], acc);
                acc = fmaf(f.y, sW[(wbase + 2*d + 1)*12 + o], acc);
            }
        }
        out[((size_t)(b*HOR + o))*NN + nd] = acc;
    }
}

extern "C" void kernel_launch(void* const* d_in, const int* in_sizes, int n_in,
                              void* d_out, int out_size, void* d_ws, size_t ws_size,
                              hipStream_t stream) {
    const float* x      = (const float*)d_in[0];
    const int*   ei     = (const int*)d_in[1];
    const float* ew     = (const float*)d_in[2];
    const float* enc_w  = (const float*)d_in[3];
    const float* enc_b  = (const float*)d_in[4];
    const float* nemb   = (const float*)d_in[5];
    const float* w_ih   = (const float*)d_in[6];
    const float* w_hh   = (const float*)d_in[7];
    const float* b_ih   = (const float*)d_in[8];
    const float* b_hh   = (const float*)d_in[9];
    const float* filt_w = (const float*)d_in[10];
    const float* filt_b = (const float*)d_in[11];
    const float* dec_w  = (const float*)d_in[12];
    const float* dec_b  = (const float*)d_in[13];
    float* out = (float*)d_out;

    char* p = (char*)d_ws;
    auto alloc = [&](size_t bytes) -> char* {
        char* q = p; p += (bytes + 255) & ~(size_t)255; return q;
    };
    // zero-region (k_zero): cnt_f, cnt_b
    char* zero_base = p;
    int*   cnt_f = (int*)  alloc((size_t)NN*4);
    int*   cnt_b = (int*)  alloc((size_t)NN*4);
    size_t zero_bytes = (size_t)(p - zero_base);
    int zero_n4 = (int)(zero_bytes / 16);

    const size_t SROW = (size_t)BB*NN*HH;
    __half* h16    = (__half*)alloc(SROW*2);
    __half* a16    = (__half*)alloc(SROW*2);
    __half* c16    = (__half*)alloc(SROW*2);
    float* CB     = (float*)alloc((size_t)NN*96*4);
    float* A      = (float*)alloc(96*4);
    float* W2     = (float*)alloc(1920*4);
    float* b2     = (float*)alloc(12*4);
    int*   off_f  = (int*)  alloc((size_t)(NN+1)*4);
    int*   off_b  = (int*)  alloc((size_t)(NN+1)*4);
    int*   rank_f = (int*)  alloc((size_t)EE*4);
    int*   rank_b = (int*)  alloc((size_t)EE*4);
    ull*   cfe    = (ull*)  alloc((size_t)EE*8);
    ull*   cbe    = (ull*)  alloc((size_t)EE*8);

    k_zero<<<(zero_n4 + 255)/256, 256, 0, stream>>>((uint4*)zero_base, zero_n4);

    k_cbhist<<<NCB + 1 + EE/256, 256, 0, stream>>>(nemb, enc_b, w_ih, b_ih, b_hh,
                                       enc_w, filt_w, filt_b, dec_w, dec_b,
                                       CB, A, W2, b2, ei, cnt_f, cnt_b,
                                       rank_f, rank_b);
    k_scan<<<2, 1024, 0, stream>>>(cnt_f, off_f, cnt_b, off_b);

    k_grufill<<<2500, 256, 0, stream>>>(x, CB, A, w_hh, b_hh, h16,
                                        ei, ew, off_f, rank_f, cfe,
                                        off_b, rank_b, cbe);

    k_prop<<<20000, 256, 0, stream>>>(h16, a16, c16,
                                      off_f, cfe, off_b, cbe);
    k_prop2dec<<<20000, 256, 0, stream>>>(a16, c16, h16,
                                          off_f, cfe, off_b, cbe,
                                          W2, b2, out);
}

// Round 17
// 196.681 us; speedup vs baseline: 1.4156x; 1.4156x over previous
//
#include <hip/hip_runtime.h>
#include <hip/hip_fp16.h>

#define BB 8
#define TT 12
#define NN 10000
#define HH 32
#define EE 320000
#define HOR 12
#define NCB 157   // ceil(NN/64) CB blocks in k_cbhist

typedef unsigned long long ull;

static __device__ __forceinline__ float sigm(float x) {
    return __builtin_amdgcn_rcpf(1.0f + __expf(-x));
}
static __device__ __forceinline__ float tanh_fast(float x) {
    return 1.0f - 2.0f * __builtin_amdgcn_rcpf(1.0f + __expf(2.0f * x));
}
static __device__ __forceinline__ float2 uph2(unsigned u) {
    __half2 h = *(__half2*)&u;
    return __half22float2(h);
}
static __device__ __forceinline__ unsigned pkh2(float a, float b) {
    __half2 h = __floats2half2_rn(a, b);
    return *(unsigned*)&h;
}

typedef _Float16 f16x4 __attribute__((ext_vector_type(4)));
typedef float    f32x4 __attribute__((ext_vector_type(4)));

// ---- zero the counter region
__global__ void k_zero(uint4* __restrict__ p, int n4) {
    int i = blockIdx.x * blockDim.x + threadIdx.x;
    if (i < n4) p[i] = (uint4){0u, 0u, 0u, 0u};
}

// ---- fused: CB GEMM-style (0..156), tiny prep (157), edge histogram+RANK (158..1407)
__global__ void k_cbhist(const float* __restrict__ node_emb, const float* __restrict__ enc_b,
                     const float* __restrict__ w_ih, const float* __restrict__ b_ih,
                     const float* __restrict__ b_hh,
                     const float* __restrict__ enc_w, const float* __restrict__ filt_w,
                     const float* __restrict__ filt_b, const float* __restrict__ dec_w,
                     const float* __restrict__ dec_b,
                     float* __restrict__ CB, float* __restrict__ A,
                     float* __restrict__ W2, float* __restrict__ b2,
                     const int* __restrict__ ei,
                     int* cnt_f, int* cnt_b,
                     int* __restrict__ rank_f, int* __restrict__ rank_b) {
    __shared__ float sw[96*36];
    __shared__ float semb[64*36];
    __shared__ float sbias[96];
    int bid = blockIdx.x;
    int tid = threadIdx.x;
    if (bid < NCB) {               // CB: 64 nodes/block, LDS-staged, coalesced
        int n0 = bid * 64;
        for (int i = tid; i < 96*32; i += 256) {
            int g = i >> 5, h = i & 31;
            sw[g*36 + h] = w_ih[i];
        }
        for (int i = tid; i < 64*32; i += 256) {
            int row = i >> 5, h = i & 31;
            int n = n0 + row; if (n >= NN) n = NN-1;
            semb[row*36 + h] = enc_b[h] + node_emb[(size_t)n*32 + h];
        }
        if (tid < 96) sbias[tid] = b_ih[tid] + (tid < 64 ? b_hh[tid] : 0.f);
        __syncthreads();
        #pragma unroll 1
        for (int i = 0; i < 24; i++) {
            int o = i*256 + tid;
            int row = o / 96, g = o - row*96;
            int n = n0 + row;
            if (n < NN) {
                float s = sbias[g];
                const float4* ev = (const float4*)(semb + row*36);
                const float4* wv = (const float4*)(sw + g*36);
                #pragma unroll
                for (int q = 0; q < 8; q++) {
                    float4 e = ev[q], w = wv[q];
                    s = fmaf(e.x, w.x, s); s = fmaf(e.y, w.y, s);
                    s = fmaf(e.z, w.z, s); s = fmaf(e.w, w.w, s);
                }
                CB[(size_t)n*96 + g] = s;
            }
        }
    } else if (bid == NCB) {       // prep
        for (int i = tid; i < 96 + 160*12 + 12; i += blockDim.x) {
            if (i < 96) {
                float s = 0.f;
                for (int h = 0; h < HH; h++) s += enc_w[h] * w_ih[i*HH + h];
                A[i] = s;
            } else if (i < 96 + 1920) {
                int j = i - 96; int c = j / 12, o = j % 12;
                float s = 0.f;
                for (int h = 0; h < HH; h++) s += filt_w[c*HH + h] * dec_w[h*12 + o];
                W2[j] = s;
            } else {
                int o = i - 2016;
                float s = dec_b[o];
                for (int h = 0; h < HH; h++) s += filt_b[h] * dec_w[h*12 + o];
                b2[o] = s;
            }
        }
    } else {                       // histogram + rank capture
        int e = (bid - NCB - 1) * 256 + tid;
        int s = ei[e], t = ei[EE + e];
        rank_f[e] = atomicAdd(&cnt_f[t], 1);
        rank_b[e] = atomicAdd(&cnt_b[s], 1);
    }
}

// ---- single-block exclusive scan (2 blocks: fwd / bwd)
__global__ void k_scan(const int* __restrict__ cnt_f, int* off_f,
                       const int* __restrict__ cnt_b, int* off_b) {
    const int* cnt; int* off;
    if (blockIdx.x == 0) { cnt = cnt_f; off = off_f; }
    else                 { cnt = cnt_b; off = off_b; }
    __shared__ int part[1024];
    int t = threadIdx.x;
    const int CH = (NN + 1023) / 1024;  // 10
    int beg = t * CH, end = min(beg + CH, NN);
    int s = 0;
    for (int i = beg; i < end; i++) s += cnt[i];
    part[t] = s;
    __syncthreads();
    for (int d = 1; d < 1024; d <<= 1) {
        int add = (t >= d) ? part[t - d] : 0;
        __syncthreads();
        part[t] += add;
        __syncthreads();
    }
    int run = part[t] - s;
    for (int i = beg; i < end; i++) {
        off[i] = run; run += cnt[i];
    }
    if (t == 1023) off[NN] = part[1023];
}

// ---- fused GRU (blocks 0..1249) + atomic-free CSR fill (blocks 1250..2499)
// GRU output in 2-SLICE layout: [slice=b>>2][n][b&3][h] fp16 (256B rows) so
// diffusion gathers have a 2.56MB/slice working set (fits one XCD's 4MB L2).
__global__ __launch_bounds__(256) void k_grufill(const float* __restrict__ x,
                      const float* __restrict__ CB, const float* __restrict__ Ag,
                      const float* __restrict__ w_hh, const float* __restrict__ b_hh,
                      __half* __restrict__ hout16,
                      const int* __restrict__ ei, const float* __restrict__ ew,
                      const int* __restrict__ off_f, const int* __restrict__ rank_f,
                      ull* __restrict__ cfe,
                      const int* __restrict__ off_b, const int* __restrict__ rank_b,
                      ull* __restrict__ cbe) {
    int tid = threadIdx.x;
    if (blockIdx.x >= 1250) {      // ---- fill: packed (w<<32|idx), atomic-free
        int e = (blockIdx.x - 1250) * 256 + tid;
        int s = ei[e], t = ei[EE + e]; float w = ew[e];
        ull wb = (ull)__float_as_uint(w) << 32;
        cfe[off_f[t] + rank_f[e]] = wb | (unsigned)s;
        cbe[off_b[s] + rank_b[e]] = wb | (unsigned)t;
        return;
    }
    // ---- MFMA GRU section (verified, unchanged logic)
    __shared__ unsigned sW[1536];
    __shared__ __half  shh[4][16*40];
    __shared__ float   sx[64][12];
    int r0b = blockIdx.x * 64;

    for (int d = tid; d < 1536; d += 256) {
        int fi = d >> 1, epair = d & 1;
        int l = fi & 63, tk = fi >> 6;
        int gt = tk >> 1, kh = tk & 1;
        int gate = 16*gt + (l & 15);
        int k = kh*16 + ((l >> 4) << 2) + 2*epair;
        sW[d] = pkh2(w_hh[gate*32 + k], w_hh[gate*32 + k + 1]);
    }
    for (int i = tid; i < 64*12; i += 256) {
        int row = i / 12, t = i - row*12;
        int r = r0b + row; int b = r / NN, n = r - b*NN;
        sx[row][t] = x[((size_t)b*TT + t)*NN + n];
    }
    __syncthreads();

    const int wv = tid >> 6, l = tid & 63;
    const int c = l & 15, m = l >> 4;
    const int r0w = r0b + wv*16;

    int bb[4], nn_[4];
    #pragma unroll
    for (int q = 0; q < 4; q++) {
        int r = r0w + 4*m + q;
        bb[q] = r / NN; nn_[q] = r - bb[q]*NN;
    }

    float cNx[2][4];
    f32x4 crv[2], czv[2], cnv[2];
    float aRj[2], aZj[2], aNj[2], bn0c[2];
    #pragma unroll
    for (int t2 = 0; t2 < 2; t2++) {
        int j = 16*t2 + c;
        #pragma unroll
        for (int q = 0; q < 4; q++) {
            const float* cb = CB + (size_t)nn_[q]*96;
            crv[t2][q] = cb[j];
            czv[t2][q] = cb[32 + j];
            cNx[t2][q] = cb[64 + j];
        }
        bn0c[t2] = b_hh[64 + j];
        cnv[t2] = (f32x4){bn0c[t2], bn0c[t2], bn0c[t2], bn0c[t2]};
        aRj[t2] = Ag[j]; aZj[t2] = Ag[32 + j]; aNj[t2] = Ag[64 + j];
    }

    f16x4 bf[12];
    #pragma unroll
    for (int i = 0; i < 12; i++) {
        ull v = *(const ull*)(sW + (i*64 + l)*2);
        bf[i] = __builtin_bit_cast(f16x4, v);
    }

    __half* hb = shh[wv];
    float own[2][4];
    {
        #pragma unroll
        for (int t2 = 0; t2 < 2; t2++)
        #pragma unroll
        for (int q = 0; q < 4; q++) {
            float xv = sx[wv*16 + 4*m + q][0];
            float rr = sigm(fmaf(xv, aRj[t2], crv[t2][q]));
            float zz = sigm(fmaf(xv, aZj[t2], czv[t2][q]));
            float nv = tanh_fast(fmaf(xv, aNj[t2], cNx[t2][q]) + rr * bn0c[t2]);
            own[t2][q] = (1.f - zz) * nv;
        }
    }
    #pragma unroll
    for (int t2 = 0; t2 < 2; t2++)
    #pragma unroll
    for (int q = 0; q < 4; q++)
        hb[(4*m + q)*40 + 16*t2 + c] = __float2half_rn(own[t2][q]);

    #pragma unroll 1
    for (int t = 1; t < TT; t++) {
        asm volatile("s_waitcnt lgkmcnt(0)" ::: "memory");
        __builtin_amdgcn_sched_barrier(0);
        ull va0 = *(const ull*)(hb + c*40 + m*4);
        ull va1 = *(const ull*)(hb + c*40 + 16 + m*4);
        f16x4 a0 = __builtin_bit_cast(f16x4, va0);
        f16x4 a1 = __builtin_bit_cast(f16x4, va1);
        float xq[4];
        #pragma unroll
        for (int q = 0; q < 4; q++) xq[q] = sx[wv*16 + 4*m + q][t];

        f32x4 aR[2], aZ[2], aN[2];
        #pragma unroll
        for (int t2 = 0; t2 < 2; t2++) {
            aR[t2] = __builtin_amdgcn_mfma_f32_16x16x16f16(a0, bf[(t2    )*2    ], crv[t2], 0, 0, 0);
            aR[t2] = __builtin_amdgcn_mfma_f32_16x16x16f16(a1, bf[(t2    )*2 + 1], aR[t2], 0, 0, 0);
            aZ[t2] = __builtin_amdgcn_mfma_f32_16x16x16f16(a0, bf[(2 + t2)*2    ], czv[t2], 0, 0, 0);
            aZ[t2] = __builtin_amdgcn_mfma_f32_16x16x16f16(a1, bf[(2 + t2)*2 + 1], aZ[t2], 0, 0, 0);
            aN[t2] = __builtin_amdgcn_mfma_f32_16x16x16f16(a0, bf[(4 + t2)*2    ], cnv[t2], 0, 0, 0);
            aN[t2] = __builtin_amdgcn_mfma_f32_16x16x16f16(a1, bf[(4 + t2)*2 + 1], aN[t2], 0, 0, 0);
        }
        #pragma unroll
        for (int t2 = 0; t2 < 2; t2++)
        #pragma unroll
        for (int q = 0; q < 4; q++) {
            float rr = sigm(fmaf(xq[q], aRj[t2], aR[t2][q]));
            float zz = sigm(fmaf(xq[q], aZj[t2], aZ[t2][q]));
            float nv = tanh_fast(fmaf(xq[q], aNj[t2], cNx[t2][q]) + rr * aN[t2][q]);
            own[t2][q] = (1.f - zz) * nv + zz * own[t2][q];
        }
        if (t < TT-1) {
            #pragma unroll
            for (int t2 = 0; t2 < 2; t2++)
            #pragma unroll
            for (int q = 0; q < 4; q++)
                hb[(4*m + q)*40 + 16*t2 + c] = __float2half_rn(own[t2][q]);
        }
    }
    #pragma unroll
    for (int t2 = 0; t2 < 2; t2++)
    #pragma unroll
    for (int q = 0; q < 4; q++) {
        size_t idx = ((size_t)((bb[q] >> 2)*NN + nn_[q]) << 7)
                   + ((bb[q] & 3) << 5) + 16*t2 + c;
        hout16[idx] = __float2half(own[t2][q]);
    }
}

// ---- 256B-row gather: lane l owns dword l of the row (64 dwords); ef loads
// CACHED (L2-shared across waves; R16's NT re-reads were the regression).
// 8-edge unroll = 8 gather chains in flight. ws accumulated per-lane (uniform).
static __device__ __forceinline__ void gather64(
        const unsigned* __restrict__ xu, unsigned rowbase /*s*NN*/,
        const ull* __restrict__ ef, int e0, int e1, int l,
        float& a0, float& a1) {
    float ws = 0.f;
    a0 = 0.f; a1 = 0.f;
    int e = e0;
    for (; e + 8 <= e1; e += 8) {
        ull q0 = ef[e],   q1 = ef[e+1], q2 = ef[e+2], q3 = ef[e+3];
        ull q4 = ef[e+4], q5 = ef[e+5], q6 = ef[e+6], q7 = ef[e+7];
        float w0 = __uint_as_float((unsigned)(q0 >> 32)), w1 = __uint_as_float((unsigned)(q1 >> 32));
        float w2 = __uint_as_float((unsigned)(q2 >> 32)), w3 = __uint_as_float((unsigned)(q3 >> 32));
        float w4 = __uint_as_float((unsigned)(q4 >> 32)), w5 = __uint_as_float((unsigned)(q5 >> 32));
        float w6 = __uint_as_float((unsigned)(q6 >> 32)), w7 = __uint_as_float((unsigned)(q7 >> 32));
        unsigned u0 = xu[((size_t)(rowbase + (unsigned)q0) << 6) + l];
        unsigned u1 = xu[((size_t)(rowbase + (unsigned)q1) << 6) + l];
        unsigned u2 = xu[((size_t)(rowbase + (unsigned)q2) << 6) + l];
        unsigned u3 = xu[((size_t)(rowbase + (unsigned)q3) << 6) + l];
        unsigned u4 = xu[((size_t)(rowbase + (unsigned)q4) << 6) + l];
        unsigned u5 = xu[((size_t)(rowbase + (unsigned)q5) << 6) + l];
        unsigned u6 = xu[((size_t)(rowbase + (unsigned)q6) << 6) + l];
        unsigned u7 = xu[((size_t)(rowbase + (unsigned)q7) << 6) + l];
        ws += ((w0 + w1) + (w2 + w3)) + ((w4 + w5) + (w6 + w7));
        float2 f;
        f = uph2(u0); a0 = fmaf(w0, f.x, a0); a1 = fmaf(w0, f.y, a1);
        f = uph2(u1); a0 = fmaf(w1, f.x, a0); a1 = fmaf(w1, f.y, a1);
        f = uph2(u2); a0 = fmaf(w2, f.x, a0); a1 = fmaf(w2, f.y, a1);
        f = uph2(u3); a0 = fmaf(w3, f.x, a0); a1 = fmaf(w3, f.y, a1);
        f = uph2(u4); a0 = fmaf(w4, f.x, a0); a1 = fmaf(w4, f.y, a1);
        f = uph2(u5); a0 = fmaf(w5, f.x, a0); a1 = fmaf(w5, f.y, a1);
        f = uph2(u6); a0 = fmaf(w6, f.x, a0); a1 = fmaf(w6, f.y, a1);
        f = uph2(u7); a0 = fmaf(w7, f.x, a0); a1 = fmaf(w7, f.y, a1);
    }
    for (; e < e1; ++e) {
        ull q0 = ef[e];
        float w0 = __uint_as_float((unsigned)(q0 >> 32));
        unsigned u0 = xu[((size_t)(rowbase + (unsigned)q0) << 6) + l];
        ws += w0;
        float2 f;
        f = uph2(u0); a0 = fmaf(w0, f.x, a0); a1 = fmaf(w0, f.y, a1);
    }
    float inv = ws > 0.f ? __builtin_amdgcn_rcpf(ws) : 1.0f;
    a0 *= inv; a1 *= inv;
}

// ---- hop 1: block = 4 waves of same (slice, dir), 4 consecutive nodes.
// (s,dir) -> XCD-pair via (bid&7)>>1 round-robin heuristic (perf-only).
__global__ __launch_bounds__(256) void k_prop(
        const __half* __restrict__ h16,
        __half* __restrict__ a16, __half* __restrict__ c16,
        const int* __restrict__ offF, const ull* __restrict__ efF,
        const int* __restrict__ offB, const ull* __restrict__ efB) {
    int bid = blockIdx.x;                 // 10000 blocks
    int g = (bid & 7) >> 1;               // 0..3 = (slice, dir)
    int s = g >> 1, dir = g & 1;
    int inner = (bid >> 3) * 2 + (bid & 1);   // 0..2499
    int wid = threadIdx.x >> 6, l = threadIdx.x & 63;
    int node = inner*4 + wid;
    unsigned rowbase = (unsigned)(s * NN);
    const int* off = dir ? offB : offF;
    const ull* ef = dir ? efB : efF;
    float a0, a1;
    gather64((const unsigned*)h16, rowbase, ef, off[node], off[node+1], l, a0, a1);
    unsigned* y = (unsigned*)(dir ? c16 : a16);
    y[((size_t)(rowbase + node) << 6) + l] = pkh2(a0, a1);
}

// ---- hop 2 + decoder: block = 4 waves (2 nodes x 2 dirs) of one slice;
// fwd2/bwd2 stay in LDS; 96-thread decode covers 2 nodes x 4 batches x 12 t.
__global__ __launch_bounds__(256) void k_prop2dec(
        const __half* __restrict__ aF, const __half* __restrict__ cBk,
        const __half* __restrict__ h16,
        const int* __restrict__ offF, const ull* __restrict__ efF,
        const int* __restrict__ offB, const ull* __restrict__ efB,
        const float* __restrict__ W2, const float* __restrict__ b2,
        float* __restrict__ out) {
    __shared__ float sW[1920];
    __shared__ float sb[12];
    __shared__ unsigned spc[4][64];       // [wave=(nl,dir)][dwords of 256B row]
    int tid = threadIdx.x;
    for (int i = tid; i < 1920; i += 256) sW[i] = W2[i];
    if (tid < 12) sb[tid] = b2[tid];
    int bid = blockIdx.x;                 // 10000 blocks
    int s = (bid & 7) >> 2;               // slice -> XCD-quad
    int inner = (bid >> 3) * 4 + (bid & 3);   // 0..4999
    int node0 = inner * 2;
    int wid = tid >> 6, l = tid & 63;
    int node = node0 + (wid >> 1), dir = wid & 1;
    unsigned rowbase = (unsigned)(s * NN);
    {
        const __half* src = dir ? cBk : aF;
        const int* off = dir ? offB : offF;
        const ull* ef = dir ? efB : efF;
        float a0, a1;
        gather64((const unsigned*)src, rowbase, ef, off[node], off[node+1], l, a0, a1);
        spc[wid][l] = pkh2(a0, a1);
    }
    __syncthreads();
    if (tid < 96) {
        int p = tid / 12;            // 0..7 = (nl in 2, bl in 4)
        int o = tid - p*12;
        int nl = p >> 2, bl = p & 3;
        int nd = node0 + nl;
        int b = 4*s + bl;
        float acc = sb[o];
        size_t dbase = ((size_t)(rowbase + nd) << 6) + (bl << 4);  // 16 dwords
        // global pieces: h (W2 rows 0..31), fwd1 (32..63), bwd1 (96..127)
        const unsigned* gp[3] = {(const unsigned*)h16 + dbase,
                                 (const unsigned*)aF + dbase,
                                 (const unsigned*)cBk + dbase};
        const int wo[3] = {0, 32, 96};
        #pragma unroll
        for (int gi = 0; gi < 3; gi++) {
            const unsigned* pp = gp[gi];
            #pragma unroll
            for (int d = 0; d < 16; d++) {
                float2 f = uph2(pp[d]);
                acc = fmaf(f.x, sW[(wo[gi] + 2*d    )*12 + o], acc);
                acc = fmaf(f.y, sW[(wo[gi] + 2*d + 1)*12 + o], acc);
            }
        }
        // LDS pieces: fwd2 (rows 64..95) = spc[nl*2], bwd2 (128..159) = spc[nl*2+1]
        #pragma unroll
        for (int dd = 0; dd < 2; dd++) {
            const unsigned* pp = &spc[nl*2 + dd][bl << 4];
            int wbase = 64 + dd*64;
            #pragma unroll
            for (int d = 0; d < 16; d++) {
                float2 f = uph2(pp[d]);
                acc = fmaf(f.x, sW[(wbase + 2*d    )*12 + o], acc);
                acc = fmaf(f.y, sW[(wbase + 2*d + 1)*12 + o], acc);
            }
        }
        out[((size_t)(b*HOR + o))*NN + nd] = acc;
    }
}

extern "C" void kernel_launch(void* const* d_in, const int* in_sizes, int n_in,
                              void* d_out, int out_size, void* d_ws, size_t ws_size,
                              hipStream_t stream) {
    const float* x      = (const float*)d_in[0];
    const int*   ei     = (const int*)d_in[1];
    const float* ew     = (const float*)d_in[2];
    const float* enc_w  = (const float*)d_in[3];
    const float* enc_b  = (const float*)d_in[4];
    const float* nemb   = (const float*)d_in[5];
    const float* w_ih   = (const float*)d_in[6];
    const float* w_hh   = (const float*)d_in[7];
    const float* b_ih   = (const float*)d_in[8];
    const float* b_hh   = (const float*)d_in[9];
    const float* filt_w = (const float*)d_in[10];
    const float* filt_b = (const float*)d_in[11];
    const float* dec_w  = (const float*)d_in[12];
    const float* dec_b  = (const float*)d_in[13];
    float* out = (float*)d_out;

    char* p = (char*)d_ws;
    auto alloc = [&](size_t bytes) -> char* {
        char* q = p; p += (bytes + 255) & ~(size_t)255; return q;
    };
    // zero-region (k_zero): cnt_f, cnt_b
    char* zero_base = p;
    int*   cnt_f = (int*)  alloc((size_t)NN*4);
    int*   cnt_b = (int*)  alloc((size_t)NN*4);
    size_t zero_bytes = (size_t)(p - zero_base);
    int zero_n4 = (int)(zero_bytes / 16);

    const size_t SROW = (size_t)BB*NN*HH;
    __half* h16    = (__half*)alloc(SROW*2);
    __half* a16    = (__half*)alloc(SROW*2);
    __half* c16    = (__half*)alloc(SROW*2);
    float* CB     = (float*)alloc((size_t)NN*96*4);
    float* A      = (float*)alloc(96*4);
    float* W2     = (float*)alloc(1920*4);
    float* b2     = (float*)alloc(12*4);
    int*   off_f  = (int*)  alloc((size_t)(NN+1)*4);
    int*   off_b  = (int*)  alloc((size_t)(NN+1)*4);
    int*   rank_f = (int*)  alloc((size_t)EE*4);
    int*   rank_b = (int*)  alloc((size_t)EE*4);
    ull*   cfe    = (ull*)  alloc((size_t)EE*8);
    ull*   cbe    = (ull*)  alloc((size_t)EE*8);

    k_zero<<<(zero_n4 + 255)/256, 256, 0, stream>>>((uint4*)zero_base, zero_n4);

    k_cbhist<<<NCB + 1 + EE/256, 256, 0, stream>>>(nemb, enc_b, w_ih, b_ih, b_hh,
                                       enc_w, filt_w, filt_b, dec_w, dec_b,
                                       CB, A, W2, b2, ei, cnt_f, cnt_b,
                                       rank_f, rank_b);
    k_scan<<<2, 1024, 0, stream>>>(cnt_f, off_f, cnt_b, off_b);

    k_grufill<<<2500, 256, 0, stream>>>(x, CB, A, w_hh, b_hh, h16,
                                        ei, ew, off_f, rank_f, cfe,
                                        off_b, rank_b, cbe);

    k_prop<<<10000, 256, 0, stream>>>(h16, a16, c16,
                                      off_f, cfe, off_b, cbe);
    k_prop2dec<<<10000, 256, 0, stream>>>(a16, c16, h16,
                                          off_f, cfe, off_b, cbe,
                                          W2, b2, out);
}

// Round 18
// 181.732 us; speedup vs baseline: 1.5320x; 1.0823x over previous
//
#include <hip/hip_runtime.h>
#include <hip/hip_fp16.h>

#define BB 8
#define TT 12
#define NN 10000
#define HH 32
#define EE 320000
#define HOR 12
#define NCB 157   // ceil(NN/64) CB blocks in k_cbhist

typedef unsigned long long ull;

static __device__ __forceinline__ float sigm(float x) {
    return __builtin_amdgcn_rcpf(1.0f + __expf(-x));
}
static __device__ __forceinline__ float tanh_fast(float x) {
    return 1.0f - 2.0f * __builtin_amdgcn_rcpf(1.0f + __expf(2.0f * x));
}
static __device__ __forceinline__ float2 uph2(unsigned u) {
    __half2 h = *(__half2*)&u;
    return __half22float2(h);
}
static __device__ __forceinline__ unsigned pkh2(float a, float b) {
    __half2 h = __floats2half2_rn(a, b);
    return *(unsigned*)&h;
}

typedef _Float16 f16x4 __attribute__((ext_vector_type(4)));
typedef float    f32x4 __attribute__((ext_vector_type(4)));

// ---- zero the counter region
__global__ void k_zero(uint4* __restrict__ p, int n4) {
    int i = blockIdx.x * blockDim.x + threadIdx.x;
    if (i < n4) p[i] = (uint4){0u, 0u, 0u, 0u};
}

// ---- fused: CB GEMM-style (0..156), tiny prep (157), edge histogram+RANK (158..1407)
__global__ void k_cbhist(const float* __restrict__ node_emb, const float* __restrict__ enc_b,
                     const float* __restrict__ w_ih, const float* __restrict__ b_ih,
                     const float* __restrict__ b_hh,
                     const float* __restrict__ enc_w, const float* __restrict__ filt_w,
                     const float* __restrict__ filt_b, const float* __restrict__ dec_w,
                     const float* __restrict__ dec_b,
                     float* __restrict__ CB, float* __restrict__ A,
                     float* __restrict__ W2, float* __restrict__ b2,
                     const int* __restrict__ ei,
                     int* cnt_f, int* cnt_b,
                     int* __restrict__ rank_f, int* __restrict__ rank_b) {
    __shared__ float sw[96*36];
    __shared__ float semb[64*36];
    __shared__ float sbias[96];
    int bid = blockIdx.x;
    int tid = threadIdx.x;
    if (bid < NCB) {               // CB: 64 nodes/block, LDS-staged, coalesced
        int n0 = bid * 64;
        for (int i = tid; i < 96*32; i += 256) {
            int g = i >> 5, h = i & 31;
            sw[g*36 + h] = w_ih[i];
        }
        for (int i = tid; i < 64*32; i += 256) {
            int row = i >> 5, h = i & 31;
            int n = n0 + row; if (n >= NN) n = NN-1;
            semb[row*36 + h] = enc_b[h] + node_emb[(size_t)n*32 + h];
        }
        if (tid < 96) sbias[tid] = b_ih[tid] + (tid < 64 ? b_hh[tid] : 0.f);
        __syncthreads();
        #pragma unroll 1
        for (int i = 0; i < 24; i++) {
            int o = i*256 + tid;
            int row = o / 96, g = o - row*96;
            int n = n0 + row;
            if (n < NN) {
                float s = sbias[g];
                const float4* ev = (const float4*)(semb + row*36);
                const float4* wv = (const float4*)(sw + g*36);
                #pragma unroll
                for (int q = 0; q < 8; q++) {
                    float4 e = ev[q], w = wv[q];
                    s = fmaf(e.x, w.x, s); s = fmaf(e.y, w.y, s);
                    s = fmaf(e.z, w.z, s); s = fmaf(e.w, w.w, s);
                }
                CB[(size_t)n*96 + g] = s;
            }
        }
    } else if (bid == NCB) {       // prep
        for (int i = tid; i < 96 + 160*12 + 12; i += blockDim.x) {
            if (i < 96) {
                float s = 0.f;
                for (int h = 0; h < HH; h++) s += enc_w[h] * w_ih[i*HH + h];
                A[i] = s;
            } else if (i < 96 + 1920) {
                int j = i - 96; int c = j / 12, o = j % 12;
                float s = 0.f;
                for (int h = 0; h < HH; h++) s += filt_w[c*HH + h] * dec_w[h*12 + o];
                W2[j] = s;
            } else {
                int o = i - 2016;
                float s = dec_b[o];
                for (int h = 0; h < HH; h++) s += filt_b[h] * dec_w[h*12 + o];
                b2[o] = s;
            }
        }
    } else {                       // histogram + rank capture
        int e = (bid - NCB - 1) * 256 + tid;
        int s = ei[e], t = ei[EE + e];
        rank_f[e] = atomicAdd(&cnt_f[t], 1);
        rank_b[e] = atomicAdd(&cnt_b[s], 1);
    }
}

// ---- single-block exclusive scan (2 blocks: fwd / bwd)
__global__ void k_scan(const int* __restrict__ cnt_f, int* off_f,
                       const int* __restrict__ cnt_b, int* off_b) {
    const int* cnt; int* off;
    if (blockIdx.x == 0) { cnt = cnt_f; off = off_f; }
    else                 { cnt = cnt_b; off = off_b; }
    __shared__ int part[1024];
    int t = threadIdx.x;
    const int CH = (NN + 1023) / 1024;  // 10
    int beg = t * CH, end = min(beg + CH, NN);
    int s = 0;
    for (int i = beg; i < end; i++) s += cnt[i];
    part[t] = s;
    __syncthreads();
    for (int d = 1; d < 1024; d <<= 1) {
        int add = (t >= d) ? part[t - d] : 0;
        __syncthreads();
        part[t] += add;
        __syncthreads();
    }
    int run = part[t] - s;
    for (int i = beg; i < end; i++) {
        off[i] = run; run += cnt[i];
    }
    if (t == 1023) off[NN] = part[1023];
}

// ---- fused GRU (blocks 0..1249) + atomic-free CSR fill (blocks 1250..2499)
__global__ __launch_bounds__(256) void k_grufill(const float* __restrict__ x,
                      const float* __restrict__ CB, const float* __restrict__ Ag,
                      const float* __restrict__ w_hh, const float* __restrict__ b_hh,
                      __half* __restrict__ hout16,
                      const int* __restrict__ ei, const float* __restrict__ ew,
                      const int* __restrict__ off_f, const int* __restrict__ rank_f,
                      ull* __restrict__ cfe,
                      const int* __restrict__ off_b, const int* __restrict__ rank_b,
                      ull* __restrict__ cbe) {
    int tid = threadIdx.x;
    if (blockIdx.x >= 1250) {      // ---- fill: packed (w<<32|idx), atomic-free
        int e = (blockIdx.x - 1250) * 256 + tid;
        int s = ei[e], t = ei[EE + e]; float w = ew[e];
        ull wb = (ull)__float_as_uint(w) << 32;
        cfe[off_f[t] + rank_f[e]] = wb | (unsigned)s;
        cbe[off_b[s] + rank_b[e]] = wb | (unsigned)t;
        return;
    }
    // ---- MFMA GRU section (verified, unchanged logic)
    __shared__ unsigned sW[1536];
    __shared__ __half  shh[4][16*40];
    __shared__ float   sx[64][12];
    int r0b = blockIdx.x * 64;

    for (int d = tid; d < 1536; d += 256) {
        int fi = d >> 1, epair = d & 1;
        int l = fi & 63, tk = fi >> 6;
        int gt = tk >> 1, kh = tk & 1;
        int gate = 16*gt + (l & 15);
        int k = kh*16 + ((l >> 4) << 2) + 2*epair;
        sW[d] = pkh2(w_hh[gate*32 + k], w_hh[gate*32 + k + 1]);
    }
    for (int i = tid; i < 64*12; i += 256) {
        int row = i / 12, t = i - row*12;
        int r = r0b + row; int b = r / NN, n = r - b*NN;
        sx[row][t] = x[((size_t)b*TT + t)*NN + n];
    }
    __syncthreads();

    const int wv = tid >> 6, l = tid & 63;
    const int c = l & 15, m = l >> 4;
    const int r0w = r0b + wv*16;

    int bb[4], nn_[4];
    #pragma unroll
    for (int q = 0; q < 4; q++) {
        int r = r0w + 4*m + q;
        bb[q] = r / NN; nn_[q] = r - bb[q]*NN;
    }

    float cNx[2][4];
    f32x4 crv[2], czv[2], cnv[2];
    float aRj[2], aZj[2], aNj[2], bn0c[2];
    #pragma unroll
    for (int t2 = 0; t2 < 2; t2++) {
        int j = 16*t2 + c;
        #pragma unroll
        for (int q = 0; q < 4; q++) {
            const float* cb = CB + (size_t)nn_[q]*96;
            crv[t2][q] = cb[j];
            czv[t2][q] = cb[32 + j];
            cNx[t2][q] = cb[64 + j];
        }
        bn0c[t2] = b_hh[64 + j];
        cnv[t2] = (f32x4){bn0c[t2], bn0c[t2], bn0c[t2], bn0c[t2]};
        aRj[t2] = Ag[j]; aZj[t2] = Ag[32 + j]; aNj[t2] = Ag[64 + j];
    }

    f16x4 bf[12];
    #pragma unroll
    for (int i = 0; i < 12; i++) {
        ull v = *(const ull*)(sW + (i*64 + l)*2);
        bf[i] = __builtin_bit_cast(f16x4, v);
    }

    __half* hb = shh[wv];
    float own[2][4];
    {
        #pragma unroll
        for (int t2 = 0; t2 < 2; t2++)
        #pragma unroll
        for (int q = 0; q < 4; q++) {
            float xv = sx[wv*16 + 4*m + q][0];
            float rr = sigm(fmaf(xv, aRj[t2], crv[t2][q]));
            float zz = sigm(fmaf(xv, aZj[t2], czv[t2][q]));
            float nv = tanh_fast(fmaf(xv, aNj[t2], cNx[t2][q]) + rr * bn0c[t2]);
            own[t2][q] = (1.f - zz) * nv;
        }
    }
    #pragma unroll
    for (int t2 = 0; t2 < 2; t2++)
    #pragma unroll
    for (int q = 0; q < 4; q++)
        hb[(4*m + q)*40 + 16*t2 + c] = __float2half_rn(own[t2][q]);

    #pragma unroll 1
    for (int t = 1; t < TT; t++) {
        asm volatile("s_waitcnt lgkmcnt(0)" ::: "memory");
        __builtin_amdgcn_sched_barrier(0);
        ull va0 = *(const ull*)(hb + c*40 + m*4);
        ull va1 = *(const ull*)(hb + c*40 + 16 + m*4);
        f16x4 a0 = __builtin_bit_cast(f16x4, va0);
        f16x4 a1 = __builtin_bit_cast(f16x4, va1);
        float xq[4];
        #pragma unroll
        for (int q = 0; q < 4; q++) xq[q] = sx[wv*16 + 4*m + q][t];

        f32x4 aR[2], aZ[2], aN[2];
        #pragma unroll
        for (int t2 = 0; t2 < 2; t2++) {
            aR[t2] = __builtin_amdgcn_mfma_f32_16x16x16f16(a0, bf[(t2    )*2    ], crv[t2], 0, 0, 0);
            aR[t2] = __builtin_amdgcn_mfma_f32_16x16x16f16(a1, bf[(t2    )*2 + 1], aR[t2], 0, 0, 0);
            aZ[t2] = __builtin_amdgcn_mfma_f32_16x16x16f16(a0, bf[(2 + t2)*2    ], czv[t2], 0, 0, 0);
            aZ[t2] = __builtin_amdgcn_mfma_f32_16x16x16f16(a1, bf[(2 + t2)*2 + 1], aZ[t2], 0, 0, 0);
            aN[t2] = __builtin_amdgcn_mfma_f32_16x16x16f16(a0, bf[(4 + t2)*2    ], cnv[t2], 0, 0, 0);
            aN[t2] = __builtin_amdgcn_mfma_f32_16x16x16f16(a1, bf[(4 + t2)*2 + 1], aN[t2], 0, 0, 0);
        }
        #pragma unroll
        for (int t2 = 0; t2 < 2; t2++)
        #pragma unroll
        for (int q = 0; q < 4; q++) {
            float rr = sigm(fmaf(xq[q], aRj[t2], aR[t2][q]));
            float zz = sigm(fmaf(xq[q], aZj[t2], aZ[t2][q]));
            float nv = tanh_fast(fmaf(xq[q], aNj[t2], cNx[t2][q]) + rr * aN[t2][q]);
            own[t2][q] = (1.f - zz) * nv + zz * own[t2][q];
        }
        if (t < TT-1) {
            #pragma unroll
            for (int t2 = 0; t2 < 2; t2++)
            #pragma unroll
            for (int q = 0; q < 4; q++)
                hb[(4*m + q)*40 + 16*t2 + c] = __float2half_rn(own[t2][q]);
        }
    }
    #pragma unroll
    for (int t2 = 0; t2 < 2; t2++)
    #pragma unroll
    for (int q = 0; q < 4; q++)
        hout16[((size_t)nn_[q]*BB + bb[q])*HH + 16*t2 + c] = __float2half(own[t2][q]);
}

// ---- gather body for one (node, dir): full 512B row (uint2/lane), cached loads
static __device__ __forceinline__ void gather_node(
        const unsigned* __restrict__ xu, const ull* __restrict__ ef,
        int e0, int e1, int l, float& a0, float& a1, float& a2, float& a3) {
    float ws = 0.f;
    a0 = a1 = a2 = a3 = 0.f;
    int e = e0;
    for (; e + 8 <= e1; e += 8) {
        ull q0 = ef[e],   q1 = ef[e+1], q2 = ef[e+2], q3 = ef[e+3];
        ull q4 = ef[e+4], q5 = ef[e+5], q6 = ef[e+6], q7 = ef[e+7];
        float w0 = __uint_as_float((unsigned)(q0 >> 32)), w1 = __uint_as_float((unsigned)(q1 >> 32));
        float w2 = __uint_as_float((unsigned)(q2 >> 32)), w3 = __uint_as_float((unsigned)(q3 >> 32));
        float w4 = __uint_as_float((unsigned)(q4 >> 32)), w5 = __uint_as_float((unsigned)(q5 >> 32));
        float w6 = __uint_as_float((unsigned)(q6 >> 32)), w7 = __uint_as_float((unsigned)(q7 >> 32));
        uint2 u0 = *(const uint2*)(xu + ((size_t)(unsigned)q0 << 7) + 2*l);
        uint2 u1 = *(const uint2*)(xu + ((size_t)(unsigned)q1 << 7) + 2*l);
        uint2 u2 = *(const uint2*)(xu + ((size_t)(unsigned)q2 << 7) + 2*l);
        uint2 u3 = *(const uint2*)(xu + ((size_t)(unsigned)q3 << 7) + 2*l);
        uint2 u4 = *(const uint2*)(xu + ((size_t)(unsigned)q4 << 7) + 2*l);
        uint2 u5 = *(const uint2*)(xu + ((size_t)(unsigned)q5 << 7) + 2*l);
        uint2 u6 = *(const uint2*)(xu + ((size_t)(unsigned)q6 << 7) + 2*l);
        uint2 u7 = *(const uint2*)(xu + ((size_t)(unsigned)q7 << 7) + 2*l);
        ws += ((w0 + w1) + (w2 + w3)) + ((w4 + w5) + (w6 + w7));
        float2 f;
        f = uph2(u0.x); a0 = fmaf(w0, f.x, a0); a1 = fmaf(w0, f.y, a1);
        f = uph2(u0.y); a2 = fmaf(w0, f.x, a2); a3 = fmaf(w0, f.y, a3);
        f = uph2(u1.x); a0 = fmaf(w1, f.x, a0); a1 = fmaf(w1, f.y, a1);
        f = uph2(u1.y); a2 = fmaf(w1, f.x, a2); a3 = fmaf(w1, f.y, a3);
        f = uph2(u2.x); a0 = fmaf(w2, f.x, a0); a1 = fmaf(w2, f.y, a1);
        f = uph2(u2.y); a2 = fmaf(w2, f.x, a2); a3 = fmaf(w2, f.y, a3);
        f = uph2(u3.x); a0 = fmaf(w3, f.x, a0); a1 = fmaf(w3, f.y, a1);
        f = uph2(u3.y); a2 = fmaf(w3, f.x, a2); a3 = fmaf(w3, f.y, a3);
        f = uph2(u4.x); a0 = fmaf(w4, f.x, a0); a1 = fmaf(w4, f.y, a1);
        f = uph2(u4.y); a2 = fmaf(w4, f.x, a2); a3 = fmaf(w4, f.y, a3);
        f = uph2(u5.x); a0 = fmaf(w5, f.x, a0); a1 = fmaf(w5, f.y, a1);
        f = uph2(u5.y); a2 = fmaf(w5, f.x, a2); a3 = fmaf(w5, f.y, a3);
        f = uph2(u6.x); a0 = fmaf(w6, f.x, a0); a1 = fmaf(w6, f.y, a1);
        f = uph2(u6.y); a2 = fmaf(w6, f.x, a2); a3 = fmaf(w6, f.y, a3);
        f = uph2(u7.x); a0 = fmaf(w7, f.x, a0); a1 = fmaf(w7, f.y, a1);
        f = uph2(u7.y); a2 = fmaf(w7, f.x, a2); a3 = fmaf(w7, f.y, a3);
    }
    for (; e < e1; ++e) {
        ull q0 = ef[e];
        float w0 = __uint_as_float((unsigned)(q0 >> 32));
        uint2 u0 = *(const uint2*)(xu + ((size_t)(unsigned)q0 << 7) + 2*l);
        ws += w0;
        float2 f;
        f = uph2(u0.x); a0 = fmaf(w0, f.x, a0); a1 = fmaf(w0, f.y, a1);
        f = uph2(u0.y); a2 = fmaf(w0, f.x, a2); a3 = fmaf(w0, f.y, a3);
    }
    float inv = ws > 0.f ? __builtin_amdgcn_rcpf(ws) : 1.0f;
    a0 *= inv; a1 *= inv; a2 *= inv; a3 *= inv;
}

// ---- hop 1: dir pinned to bid&1 (each XCD under bid%8 round-robin streams
// only one CSR). 4 waves = 4 consecutive nodes of that dir. 5000 blocks.
__global__ __launch_bounds__(256) void k_prop(
        const __half* __restrict__ xF, const __half* __restrict__ xB,
        __half* __restrict__ yF16, __half* __restrict__ yB16,
        const int* __restrict__ offF, const ull* __restrict__ efF,
        const int* __restrict__ offB, const ull* __restrict__ efB) {
    int bid = blockIdx.x;
    int dir = bid & 1;
    int n = (bid >> 1) * 4 + (threadIdx.x >> 6);   // 2500*4 = NN
    int l = threadIdx.x & 63;
    const unsigned* xu = (const unsigned*)(dir ? xB : xF);
    const int* off = dir ? offB : offF;
    const ull* ef = dir ? efB : efF;
    float a0, a1, a2, a3;
    gather_node(xu, ef, off[n], off[n+1], l, a0, a1, a2, a3);
    unsigned* yh = (unsigned*)(dir ? yB16 : yF16);
    uint2 oh; oh.x = pkh2(a0, a1); oh.y = pkh2(a2, a3);
    *(uint2*)(yh + ((size_t)n << 7) + 2*l) = oh;
}

// ---- hop 2 + decoder fused (R15 version, measured best)
__global__ __launch_bounds__(256) void k_prop2dec(
        const __half* __restrict__ aF, const __half* __restrict__ cBk,
        const __half* __restrict__ h16,
        const int* __restrict__ offF, const ull* __restrict__ efF,
        const int* __restrict__ offB, const ull* __restrict__ efB,
        const float* __restrict__ W2, const float* __restrict__ b2,
        float* __restrict__ out) {
    __shared__ float sW[1920];
    __shared__ float sb[12];
    __shared__ unsigned spc[4][2][128];   // [node][dir][dwords of 256-fp16 row]
    int tid = threadIdx.x;
    for (int i = tid; i < 1920; i += 256) sW[i] = W2[i];
    if (tid < 12) sb[tid] = b2[tid];
    int wv = tid >> 6, l = tid & 63;
    int n = blockIdx.x * 4 + wv;          // 2500 blocks exactly
    {   // fwd hop 2 (from a16)
        float a0, a1, a2, a3;
        gather_node((const unsigned*)aF, efF, offF[n], offF[n+1], l, a0, a1, a2, a3);
        spc[wv][0][2*l]   = pkh2(a0, a1);
        spc[wv][0][2*l+1] = pkh2(a2, a3);
    }
    {   // bwd hop 2 (from c16)
        float a0, a1, a2, a3;
        gather_node((const unsigned*)cBk, efB, offB[n], offB[n+1], l, a0, a1, a2, a3);
        spc[wv][1][2*l]   = pkh2(a0, a1);
        spc[wv][1][2*l+1] = pkh2(a2, a3);
    }
    __syncthreads();
    if (tid < 128) {
        int nl = tid >> 5;           // 0..3
        int b  = (tid >> 2) & 7;     // 0..7
        int tq = tid & 3;            // t-quarter: outputs 3*tq..3*tq+2
        int node = blockIdx.x * 4 + nl;
        size_t base = ((size_t)node * BB + b) * HH;
        float a[3];
        #pragma unroll
        for (int o = 0; o < 3; o++) a[o] = sb[3*tq + o];
        const __half* gp[3] = {h16, aF, cBk};
        const int wo[3] = {0, 32, 96};
        #pragma unroll
        for (int gi = 0; gi < 3; gi++) {
            const uint4* pp = (const uint4*)(gp[gi] + base);
            const float* wbase = sW + wo[gi]*12 + 3*tq;
            #pragma unroll
            for (int q = 0; q < 4; q++) {
                uint4 v = pp[q];
                float2 f0 = uph2(v.x), f1 = uph2(v.y), f2 = uph2(v.z), f3 = uph2(v.w);
                float pv[8] = {f0.x, f0.y, f1.x, f1.y, f2.x, f2.y, f3.x, f3.y};
                #pragma unroll
                for (int k = 0; k < 8; k++) {
                    const float* wrow = wbase + (q*8 + k)*12;
                    #pragma unroll
                    for (int o = 0; o < 3; o++) a[o] = fmaf(pv[k], wrow[o], a[o]);
                }
            }
        }
        #pragma unroll
        for (int dir = 0; dir < 2; dir++) {
            const uint4* pp = (const uint4*)&spc[nl][dir][b*16];
            const float* wbase = sW + (64 + dir*64)*12 + 3*tq;
            #pragma unroll
            for (int q = 0; q < 4; q++) {
                uint4 v = pp[q];
                float2 f0 = uph2(v.x), f1 = uph2(v.y), f2 = uph2(v.z), f3 = uph2(v.w);
                float pv[8] = {f0.x, f0.y, f1.x, f1.y, f2.x, f2.y, f3.x, f3.y};
                #pragma unroll
                for (int k = 0; k < 8; k++) {
                    const float* wrow = wbase + (q*8 + k)*12;
                    #pragma unroll
                    for (int o = 0; o < 3; o++) a[o] = fmaf(pv[k], wrow[o], a[o]);
                }
            }
        }
        #pragma unroll
        for (int o = 0; o < 3; o++)
            out[((size_t)(b*HOR + 3*tq + o))*NN + node] = a[o];
    }
}

extern "C" void kernel_launch(void* const* d_in, const int* in_sizes, int n_in,
                              void* d_out, int out_size, void* d_ws, size_t ws_size,
                              hipStream_t stream) {
    const float* x      = (const float*)d_in[0];
    const int*   ei     = (const int*)d_in[1];
    const float* ew     = (const float*)d_in[2];
    const float* enc_w  = (const float*)d_in[3];
    const float* enc_b  = (const float*)d_in[4];
    const float* nemb   = (const float*)d_in[5];
    const float* w_ih   = (const float*)d_in[6];
    const float* w_hh   = (const float*)d_in[7];
    const float* b_ih   = (const float*)d_in[8];
    const float* b_hh   = (const float*)d_in[9];
    const float* filt_w = (const float*)d_in[10];
    const float* filt_b = (const float*)d_in[11];
    const float* dec_w  = (const float*)d_in[12];
    const float* dec_b  = (const float*)d_in[13];
    float* out = (float*)d_out;

    char* p = (char*)d_ws;
    auto alloc = [&](size_t bytes) -> char* {
        char* q = p; p += (bytes + 255) & ~(size_t)255; return q;
    };
    // zero-region (k_zero): cnt_f, cnt_b
    char* zero_base = p;
    int*   cnt_f = (int*)  alloc((size_t)NN*4);
    int*   cnt_b = (int*)  alloc((size_t)NN*4);
    size_t zero_bytes = (size_t)(p - zero_base);
    int zero_n4 = (int)(zero_bytes / 16);

    const size_t SROW = (size_t)BB*NN*HH;
    __half* h16    = (__half*)alloc(SROW*2);
    __half* a16    = (__half*)alloc(SROW*2);
    __half* c16    = (__half*)alloc(SROW*2);
    float* CB     = (float*)alloc((size_t)NN*96*4);
    float* A      = (float*)alloc(96*4);
    float* W2     = (float*)alloc(1920*4);
    float* b2     = (float*)alloc(12*4);
    int*   off_f  = (int*)  alloc((size_t)(NN+1)*4);
    int*   off_b  = (int*)  alloc((size_t)(NN+1)*4);
    int*   rank_f = (int*)  alloc((size_t)EE*4);
    int*   rank_b = (int*)  alloc((size_t)EE*4);
    ull*   cfe    = (ull*)  alloc((size_t)EE*8);
    ull*   cbe    = (ull*)  alloc((size_t)EE*8);

    k_zero<<<(zero_n4 + 255)/256, 256, 0, stream>>>((uint4*)zero_base, zero_n4);

    k_cbhist<<<NCB + 1 + EE/256, 256, 0, stream>>>(nemb, enc_b, w_ih, b_ih, b_hh,
                                       enc_w, filt_w, filt_b, dec_w, dec_b,
                                       CB, A, W2, b2, ei, cnt_f, cnt_b,
                                       rank_f, rank_b);
    k_scan<<<2, 1024, 0, stream>>>(cnt_f, off_f, cnt_b, off_b);

    k_grufill<<<2500, 256, 0, stream>>>(x, CB, A, w_hh, b_hh, h16,
                                        ei, ew, off_f, rank_f, cfe,
                                        off_b, rank_b, cbe);

    k_prop<<<5000, 256, 0, stream>>>(h16, h16, a16, c16,
                                     off_f, cfe, off_b, cbe);
    k_prop2dec<<<2500, 256, 0, stream>>>(a16, c16, h16,
                                         off_f, cfe, off_b, cbe,
                                         W2, b2, out);
}